// Round 1
// baseline (23429.956 us; speedup 1.0000x reference)
//
#include <hip/hip_runtime.h>
#include <cstddef>

#define TSTEPS 4096
#define INLEN  1910
#define NROW   40
#define NCOL   50
#define NCELL  2000
#define PW     52          // padded width  (50 + 2 halo)
#define PH     42          // padded height (40 + 2 halo)
#define NTHR   512

__device__ __forceinline__ float fastrcp(float x) { return __builtin_amdgcn_rcpf(x); }
__device__ __forceinline__ float sigm(float x)    { return fastrcp(1.0f + __expf(-x)); }
// overflow-safe tanh: 2*sigmoid(2x)-1
__device__ __forceinline__ float tanh_f(float x)  { return 2.0f * fastrcp(1.0f + __expf(-2.0f * x)) - 1.0f; }

// One ConvLSTM cell update for the 4 cells this thread owns.
// xf: input field (padded, LDS), hf: hidden field (padded, LDS)
// wr: 72 weights [gate(4)][ch(2)][9]; br: 4 biases; cst: cell state (regs); hn: new hidden out
__device__ __forceinline__ void cell_update(const float* __restrict__ xf,
                                            const float* __restrict__ hf,
                                            const float (&wr)[72], const float (&br)[4],
                                            const int (&pidx)[4],
                                            float (&cst)[4], float (&hn)[4]) {
#pragma unroll
    for (int q = 0; q < 4; ++q) {
        const int p = pidx[q];
        float z0 = br[0], z1 = br[1], z2 = br[2], z3 = br[3];
#pragma unroll
        for (int ky = 0; ky < 3; ++ky) {
#pragma unroll
            for (int kx = 0; kx < 3; ++kx) {
                const int off = (ky - 1) * PW + (kx - 1);
                const float xval = xf[p + off];
                const float hval = hf[p + off];
                const int wi = ky * 3 + kx;
                z0 += wr[ 0 + wi] * xval + wr[ 9 + wi] * hval;
                z1 += wr[18 + wi] * xval + wr[27 + wi] * hval;
                z2 += wr[36 + wi] * xval + wr[45 + wi] * hval;
                z3 += wr[54 + wi] * xval + wr[63 + wi] * hval;
            }
        }
        const float ig = sigm(z0);
        const float fg = sigm(z1);
        const float og = sigm(z2);
        const float gg = tanh_f(z3);
        const float cn = fg * cst[q] + ig * gg;
        cst[q] = cn;
        hn[q]  = og * tanh_f(cn);
    }
}

__global__ __launch_bounds__(NTHR, 2) void convlstm_scan(
    const float* __restrict__ s,
    const float* __restrict__ w0g, const float* __restrict__ b0g,
    const float* __restrict__ w1g, const float* __restrict__ b1g,
    float* __restrict__ feat) {
    __shared__ float xb[PH * PW];
    __shared__ float h0[PH * PW];
    __shared__ float h1[PH * PW];

    const int tid = threadIdx.x;

    // zero all LDS fields (halo stays zero forever => 'SAME' zero padding)
    for (int i = tid; i < PH * PW; i += NTHR) { xb[i] = 0.f; h0[i] = 0.f; h1[i] = 0.f; }

    // weights -> registers
    float w0r[72], w1r[72], b0r[4], b1r[4];
#pragma unroll
    for (int i = 0; i < 72; ++i) w0r[i] = w0g[i];
#pragma unroll
    for (int i = 0; i < 72; ++i) w1r[i] = w1g[i];
#pragma unroll
    for (int i = 0; i < 4; ++i) { b0r[i] = b0g[i]; b1r[i] = b1g[i]; }

    // interleaved cell mapping: cell q = tid + q*512  (lane-stride-1 LDS access)
    int pidx[4];
    bool cv[4];
#pragma unroll
    for (int q = 0; q < 4; ++q) {
        int cell = tid + q * NTHR;
        cv[q] = (cell < NCELL);
        if (!cv[q]) cell = 0;
        const int r = cell / NCOL, c = cell % NCOL;
        pidx[q] = (r + 1) * PW + (c + 1);
    }

    // x staging indices (1910 valid elements per step; rest of the 2000 stay zero)
    int xjj[4], xpp[4];
    bool xv[4];
#pragma unroll
    for (int k = 0; k < 4; ++k) {
        int j = tid + k * NTHR;
        xv[k] = (j < INLEN);
        if (!xv[k]) j = 0;
        xjj[k] = j;
        const int r = j / NCOL, c = j % NCOL;
        xpp[k] = (r + 1) * PW + (c + 1);
    }

    float c0r[4] = {0.f, 0.f, 0.f, 0.f};
    float c1r[4] = {0.f, 0.f, 0.f, 0.f};

    // prefetch x(0)
    float xr[4];
#pragma unroll
    for (int k = 0; k < 4; ++k) xr[k] = xv[k] ? s[xjj[k]] : 0.f;

    __syncthreads();  // LDS zero-init visible to all

    for (int t = 0; t < TSTEPS; ++t) {
        // stage x(t) into LDS; prefetch x(t+1) into registers (latency hidden by this step)
#pragma unroll
        for (int k = 0; k < 4; ++k)
            if (xv[k]) xb[xpp[k]] = xr[k];
        {
            const size_t bofs = (size_t)(t + 1 < TSTEPS ? t + 1 : t) * INLEN;
#pragma unroll
            for (int k = 0; k < 4; ++k) xr[k] = xv[k] ? s[bofs + xjj[k]] : 0.f;
        }
        __syncthreads();  // xb ready

        // ---- layer 0: input = xb, hidden = h0 ----
        float hn0[4];
        cell_update(xb, h0, w0r, b0r, pidx, c0r, hn0);
        __syncthreads();  // all reads of old h0 done
#pragma unroll
        for (int q = 0; q < 4; ++q)
            if (cv[q]) h0[pidx[q]] = hn0[q];
        __syncthreads();  // new h0 visible

        // ---- layer 1: input = h0 (new), hidden = h1 ----
        float hn1[4];
        cell_update(h0, h1, w1r, b1r, pidx, c1r, hn1);
        __syncthreads();  // all reads of old h1 done
#pragma unroll
        for (int q = 0; q < 4; ++q)
            if (cv[q]) h1[pidx[q]] = hn1[q];
        // no barrier needed here: next iter's reads of h1 are behind 3 barriers,
        // and next iter's xb stores race with nothing (layer-0 reads of this
        // iter completed before the 2nd barrier above).
    }

    // final h1 -> feat (each thread wrote its own cells; no cross-thread read)
#pragma unroll
    for (int q = 0; q < 4; ++q)
        if (cv[q]) feat[tid + q * NTHR] = h1[pidx[q]];
}

// out[j] = sigmoid( fc_b[j] + sum_k leaky_relu(feat[k]) * fc_w[j*2000 + k] )
__global__ __launch_bounds__(256) void fc_kernel(const float* __restrict__ feat,
                                                 const float* __restrict__ w,
                                                 const float* __restrict__ b,
                                                 float* __restrict__ out) {
    const int j   = blockIdx.x;
    const int tid = threadIdx.x;
    const float* __restrict__ wr = w + (size_t)j * NCELL;

    float acc = 0.f;
    for (int k = tid; k < NCELL; k += 256) {
        float f = feat[k];
        f = (f > 0.f) ? f : 0.01f * f;
        acc += f * wr[k];
    }
    // wave reduce (64 lanes)
#pragma unroll
    for (int off = 32; off > 0; off >>= 1) acc += __shfl_down(acc, off, 64);

    __shared__ float red[4];
    const int wv = tid >> 6, ln = tid & 63;
    if (ln == 0) red[wv] = acc;
    __syncthreads();
    if (tid == 0) {
        const float a = red[0] + red[1] + red[2] + red[3] + b[j];
        out[j] = fastrcp(1.0f + __expf(-a));
    }
}

extern "C" void kernel_launch(void* const* d_in, const int* in_sizes, int n_in,
                              void* d_out, int out_size, void* d_ws, size_t ws_size,
                              hipStream_t stream) {
    const float* s   = (const float*)d_in[0];
    const float* w0  = (const float*)d_in[1];
    const float* b0  = (const float*)d_in[2];
    const float* w1  = (const float*)d_in[3];
    const float* b1  = (const float*)d_in[4];
    const float* fcw = (const float*)d_in[5];
    const float* fcb = (const float*)d_in[6];
    float* out  = (float*)d_out;
    float* feat = (float*)d_ws;  // 2000 floats of scratch

    convlstm_scan<<<1, NTHR, 0, stream>>>(s, w0, b0, w1, b1, feat);
    fc_kernel<<<NCELL, 256, 0, stream>>>(feat, fcw, fcb, out);
}

// Round 2
// 18463.574 us; speedup vs baseline: 1.2690x; 1.2690x over previous
//
#include <hip/hip_runtime.h>
#include <cstddef>

#define TSTEPS 4096
#define INLEN  1910
#define NROW   40
#define NCOL   50
#define NCELL  2000
#define NGATE  4
#define NTHR   512

// padded field dims for the pre-pass
#define PPH 42
#define PPW 52

// ---------- math helpers ----------
__device__ __forceinline__ float fastrcp(float x) { return __builtin_amdgcn_rcpf(x); }
__device__ __forceinline__ float sigm(float x)    { return fastrcp(1.0f + __expf(-x)); }
// overflow-safe tanh: 2*sigmoid(2x)-1
__device__ __forceinline__ float tanh_f(float x)  { return 2.0f * fastrcp(1.0f + __expf(-2.0f * x)) - 1.0f; }

// ---------- DPP full-wave lane shifts (zero fill at wave ends) ----------
// lane i result = src[i-1]  (value at column c-1); lane 0 -> 0
__device__ __forceinline__ float lane_left(float x) {
    int r = __builtin_amdgcn_update_dpp(0, __builtin_bit_cast(int, x),
                                        0x138 /*WAVE_SHR1*/, 0xF, 0xF, true);
    return __builtin_bit_cast(float, r);
}
// lane i result = src[i+1]  (value at column c+1); lane 63 -> 0
__device__ __forceinline__ float lane_right(float x) {
    int r = __builtin_amdgcn_update_dpp(0, __builtin_bit_cast(int, x),
                                        0x130 /*WAVE_SHL1*/, 0xF, 0xF, true);
    return __builtin_bit_cast(float, r);
}

// ============================================================================
// Pre-pass: zx[t][g][cell] = b0[g] + conv2d_x(x[t])   (data-parallel over t)
// ============================================================================
__global__ __launch_bounds__(256) void zx_prepass(const float* __restrict__ s,
                                                  const float* __restrict__ w0,
                                                  const float* __restrict__ b0,
                                                  float* __restrict__ zx) {
    __shared__ float xf[PPH * PPW];
    const int t = blockIdx.x;
    const int tid = threadIdx.x;
    for (int i = tid; i < PPH * PPW; i += 256) xf[i] = 0.f;
    __syncthreads();
    const float* __restrict__ xs = s + (size_t)t * INLEN;
    for (int j = tid; j < INLEN; j += 256) {
        const int r = j / NCOL, c = j % NCOL;
        xf[(r + 1) * PPW + (c + 1)] = xs[j];
    }
    // x-channel weights: w0[(g*2+0)*9 + k]
    float wg[4][9], bb[4];
#pragma unroll
    for (int g = 0; g < 4; ++g) {
        bb[g] = b0[g];
#pragma unroll
        for (int k = 0; k < 9; ++k) wg[g][k] = w0[(g * 2 + 0) * 9 + k];
    }
    __syncthreads();
    float* __restrict__ zt = zx + (size_t)t * (NGATE * NCELL);
    for (int cell = tid; cell < NCELL; cell += 256) {
        const int r = cell / NCOL, c = cell % NCOL;
        const int p = (r + 1) * PPW + (c + 1);
        float z0 = bb[0], z1 = bb[1], z2 = bb[2], z3 = bb[3];
#pragma unroll
        for (int ky = 0; ky < 3; ++ky)
#pragma unroll
            for (int kx = 0; kx < 3; ++kx) {
                const float v = xf[p + (ky - 1) * PPW + (kx - 1)];
                const int k = ky * 3 + kx;
                z0 += wg[0][k] * v; z1 += wg[1][k] * v;
                z2 += wg[2][k] * v; z3 += wg[3][k] * v;
            }
        zt[0 * NCELL + cell] = z0;
        zt[1 * NCELL + cell] = z1;
        zt[2 * NCELL + cell] = z2;
        zt[3 * NCELL + cell] = z3;
    }
}

// ============================================================================
// Scan kernel: single workgroup, lane = column, wave w owns rows 5w..5w+4.
// State (h,c for both layers) lives in registers; only strip-boundary rows
// go through LDS; horizontal stencil neighbors via DPP wave shifts.
// ============================================================================
__global__ __launch_bounds__(NTHR, 2) void convlstm_scan2(
        const float* __restrict__ zx,
        const float* __restrict__ w0g,
        const float* __restrict__ w1g, const float* __restrict__ b1g,
        float* __restrict__ feat) {
    __shared__ float hh0[8][2][64];  // [wave][0=row 5w, 1=row 5w+4][col]
    __shared__ float hh1[8][2][64];

    const int tid = threadIdx.x;
    const int w = tid >> 6;
    const int c = tid & 63;
    const bool colok = (c < NCOL);

    hh0[w][0][c] = 0.f; hh0[w][1][c] = 0.f;
    hh1[w][0][c] = 0.f; hh1[w][1][c] = 0.f;

    // weights (uniform across threads -> mostly SGPRs)
    float wh0[4][9], wx1[4][9], wh1[4][9], b1[4];
#pragma unroll
    for (int g = 0; g < 4; ++g) {
        b1[g] = b1g[g];
#pragma unroll
        for (int k = 0; k < 9; ++k) {
            wh0[g][k] = w0g[(g * 2 + 1) * 9 + k];  // layer-0 h-channel
            wx1[g][k] = w1g[(g * 2 + 0) * 9 + k];  // layer-1 x-channel (applied to h0)
            wh1[g][k] = w1g[(g * 2 + 1) * 9 + k];  // layer-1 h-channel
        }
    }

    const int cmin  = colok ? c : (NCOL - 1);
    const int zbase = w * 5 * NCOL + cmin;

    float h0v[5] = {0,0,0,0,0}, c0v[5] = {0,0,0,0,0};
    float h1v[5] = {0,0,0,0,0}, c1v[5] = {0,0,0,0,0};

    // prefetch zx(t=0)
    float zr[4][5];
#pragma unroll
    for (int g = 0; g < 4; ++g)
#pragma unroll
        for (int i = 0; i < 5; ++i)
            zr[g][i] = zx[g * NCELL + i * NCOL + zbase];

    __syncthreads();

    for (int t = 0; t < TSTEPS; ++t) {
        // ---- halos of h0[t-1], h1[t-1] (written before previous step's end barrier) ----
        const float h0top = (w > 0) ? hh0[w - 1][1][c] : 0.f;
        const float h0bot = (w < 7) ? hh0[w + 1][0][c] : 0.f;
        const float h1top = (w > 0) ? hh1[w - 1][1][c] : 0.f;
        const float h1bot = (w < 7) ? hh1[w + 1][0][c] : 0.f;

        // consume zx into za, then immediately issue next-step prefetch so the
        // loads complete before B1's vmcnt drain
        float za[4][5];
#pragma unroll
        for (int g = 0; g < 4; ++g)
#pragma unroll
            for (int i = 0; i < 5; ++i) za[g][i] = zr[g][i];
        {
            const int tn = (t + 1 < TSTEPS) ? (t + 1) : t;
            const float* __restrict__ zp = zx + (size_t)tn * (NGATE * NCELL);
#pragma unroll
            for (int g = 0; g < 4; ++g)
#pragma unroll
                for (int i = 0; i < 5; ++i)
                    zr[g][i] = zp[g * NCELL + i * NCOL + zbase];
        }

        // ---- layer 0: z = zx + conv_h(h0[t-1]) ----
        float e0[7] = {h0top, h0v[0], h0v[1], h0v[2], h0v[3], h0v[4], h0bot};
        float L0[7], R0[7];
#pragma unroll
        for (int r = 0; r < 7; ++r) { L0[r] = lane_left(e0[r]); R0[r] = lane_right(e0[r]); }

        float h0n[5];
#pragma unroll
        for (int i = 0; i < 5; ++i) {
            float z0 = za[0][i], z1 = za[1][i], z2 = za[2][i], z3 = za[3][i];
#pragma unroll
            for (int pr = 0; pr < 3; ++pr) {
                const int rr = i + pr;
                const int k = pr * 3;
                z0 += wh0[0][k]*L0[rr] + wh0[0][k+1]*e0[rr] + wh0[0][k+2]*R0[rr];
                z1 += wh0[1][k]*L0[rr] + wh0[1][k+1]*e0[rr] + wh0[1][k+2]*R0[rr];
                z2 += wh0[2][k]*L0[rr] + wh0[2][k+1]*e0[rr] + wh0[2][k+2]*R0[rr];
                z3 += wh0[3][k]*L0[rr] + wh0[3][k+1]*e0[rr] + wh0[3][k+2]*R0[rr];
            }
            const float ig = sigm(z0), fg = sigm(z1), og = sigm(z2), gg = tanh_f(z3);
            const float cn = fg * c0v[i] + ig * gg;
            c0v[i] = cn;
            const float hn = og * tanh_f(cn);
            h0n[i] = colok ? hn : 0.f;
        }

        __syncthreads();                   // B1: all old-halo reads complete
        hh0[w][0][c] = h0n[0];
        hh0[w][1][c] = h0n[4];
        __syncthreads();                   // B2: new h0 halos visible

        const float h0ntop = (w > 0) ? hh0[w - 1][1][c] : 0.f;
        const float h0nbot = (w < 7) ? hh0[w + 1][0][c] : 0.f;

        // ---- layer 1: z = b1 + conv_x(h0[t]) + conv_h(h1[t-1]) ----
        float ex[7] = {h0ntop, h0n[0], h0n[1], h0n[2], h0n[3], h0n[4], h0nbot};
        float eh[7] = {h1top, h1v[0], h1v[1], h1v[2], h1v[3], h1v[4], h1bot};
        float Lx[7], Rx[7], Lh[7], Rh[7];
#pragma unroll
        for (int r = 0; r < 7; ++r) {
            Lx[r] = lane_left(ex[r]); Rx[r] = lane_right(ex[r]);
            Lh[r] = lane_left(eh[r]); Rh[r] = lane_right(eh[r]);
        }

#pragma unroll
        for (int i = 0; i < 5; ++i) {
            float z0 = b1[0], z1 = b1[1], z2 = b1[2], z3 = b1[3];
#pragma unroll
            for (int pr = 0; pr < 3; ++pr) {
                const int rr = i + pr;
                const int k = pr * 3;
                z0 += wx1[0][k]*Lx[rr] + wx1[0][k+1]*ex[rr] + wx1[0][k+2]*Rx[rr]
                    + wh1[0][k]*Lh[rr] + wh1[0][k+1]*eh[rr] + wh1[0][k+2]*Rh[rr];
                z1 += wx1[1][k]*Lx[rr] + wx1[1][k+1]*ex[rr] + wx1[1][k+2]*Rx[rr]
                    + wh1[1][k]*Lh[rr] + wh1[1][k+1]*eh[rr] + wh1[1][k+2]*Rh[rr];
                z2 += wx1[2][k]*Lx[rr] + wx1[2][k+1]*ex[rr] + wx1[2][k+2]*Rx[rr]
                    + wh1[2][k]*Lh[rr] + wh1[2][k+1]*eh[rr] + wh1[2][k+2]*Rh[rr];
                z3 += wx1[3][k]*Lx[rr] + wx1[3][k+1]*ex[rr] + wx1[3][k+2]*Rx[rr]
                    + wh1[3][k]*Lh[rr] + wh1[3][k+1]*eh[rr] + wh1[3][k+2]*Rh[rr];
            }
            const float ig = sigm(z0), fg = sigm(z1), og = sigm(z2), gg = tanh_f(z3);
            const float cn = fg * c1v[i] + ig * gg;
            c1v[i] = cn;
            const float hn = og * tanh_f(cn);
            h1v[i] = colok ? hn : 0.f;
        }
#pragma unroll
        for (int i = 0; i < 5; ++i) h0v[i] = h0n[i];

        hh1[w][0][c] = h1v[0];
        hh1[w][1][c] = h1v[4];
        __syncthreads();                   // B3: h1 halos visible for next step
    }

    if (colok) {
#pragma unroll
        for (int i = 0; i < 5; ++i)
            feat[(w * 5 + i) * NCOL + c] = h1v[i];
    }
}

// ============================================================================
// Round-1 monolithic scan (fallback if d_ws can't hold zx)
// ============================================================================
#define PW 52
#define PH 42
__device__ __forceinline__ void cell_update(const float* __restrict__ xf,
                                            const float* __restrict__ hf,
                                            const float (&wr)[72], const float (&br)[4],
                                            const int (&pidx)[4],
                                            float (&cst)[4], float (&hn)[4]) {
#pragma unroll
    for (int q = 0; q < 4; ++q) {
        const int p = pidx[q];
        float z0 = br[0], z1 = br[1], z2 = br[2], z3 = br[3];
#pragma unroll
        for (int ky = 0; ky < 3; ++ky)
#pragma unroll
            for (int kx = 0; kx < 3; ++kx) {
                const int off = (ky - 1) * PW + (kx - 1);
                const float xval = xf[p + off];
                const float hval = hf[p + off];
                const int wi = ky * 3 + kx;
                z0 += wr[ 0 + wi] * xval + wr[ 9 + wi] * hval;
                z1 += wr[18 + wi] * xval + wr[27 + wi] * hval;
                z2 += wr[36 + wi] * xval + wr[45 + wi] * hval;
                z3 += wr[54 + wi] * xval + wr[63 + wi] * hval;
            }
        const float ig = sigm(z0), fg = sigm(z1), og = sigm(z2), gg = tanh_f(z3);
        const float cn = fg * cst[q] + ig * gg;
        cst[q] = cn;
        hn[q]  = og * tanh_f(cn);
    }
}

__global__ __launch_bounds__(NTHR, 2) void convlstm_scan(
    const float* __restrict__ s,
    const float* __restrict__ w0g, const float* __restrict__ b0g,
    const float* __restrict__ w1g, const float* __restrict__ b1g,
    float* __restrict__ feat) {
    __shared__ float xb[PH * PW];
    __shared__ float h0[PH * PW];
    __shared__ float h1[PH * PW];
    const int tid = threadIdx.x;
    for (int i = tid; i < PH * PW; i += NTHR) { xb[i] = 0.f; h0[i] = 0.f; h1[i] = 0.f; }
    float w0r[72], w1r[72], b0r[4], b1r[4];
#pragma unroll
    for (int i = 0; i < 72; ++i) w0r[i] = w0g[i];
#pragma unroll
    for (int i = 0; i < 72; ++i) w1r[i] = w1g[i];
#pragma unroll
    for (int i = 0; i < 4; ++i) { b0r[i] = b0g[i]; b1r[i] = b1g[i]; }
    int pidx[4]; bool cv[4];
#pragma unroll
    for (int q = 0; q < 4; ++q) {
        int cell = tid + q * NTHR;
        cv[q] = (cell < NCELL);
        if (!cv[q]) cell = 0;
        const int r = cell / NCOL, c = cell % NCOL;
        pidx[q] = (r + 1) * PW + (c + 1);
    }
    int xjj[4], xpp[4]; bool xv[4];
#pragma unroll
    for (int k = 0; k < 4; ++k) {
        int j = tid + k * NTHR;
        xv[k] = (j < INLEN);
        if (!xv[k]) j = 0;
        xjj[k] = j;
        const int r = j / NCOL, c = j % NCOL;
        xpp[k] = (r + 1) * PW + (c + 1);
    }
    float c0r[4] = {0,0,0,0}, c1r[4] = {0,0,0,0};
    float xr[4];
#pragma unroll
    for (int k = 0; k < 4; ++k) xr[k] = xv[k] ? s[xjj[k]] : 0.f;
    __syncthreads();
    for (int t = 0; t < TSTEPS; ++t) {
#pragma unroll
        for (int k = 0; k < 4; ++k)
            if (xv[k]) xb[xpp[k]] = xr[k];
        {
            const size_t bofs = (size_t)(t + 1 < TSTEPS ? t + 1 : t) * INLEN;
#pragma unroll
            for (int k = 0; k < 4; ++k) xr[k] = xv[k] ? s[bofs + xjj[k]] : 0.f;
        }
        __syncthreads();
        float hn0[4];
        cell_update(xb, h0, w0r, b0r, pidx, c0r, hn0);
        __syncthreads();
#pragma unroll
        for (int q = 0; q < 4; ++q)
            if (cv[q]) h0[pidx[q]] = hn0[q];
        __syncthreads();
        float hn1[4];
        cell_update(h0, h1, w1r, b1r, pidx, c1r, hn1);
        __syncthreads();
#pragma unroll
        for (int q = 0; q < 4; ++q)
            if (cv[q]) h1[pidx[q]] = hn1[q];
    }
#pragma unroll
    for (int q = 0; q < 4; ++q)
        if (cv[q]) feat[tid + q * NTHR] = h1[pidx[q]];
}

// ============================================================================
// FC epilogue
// ============================================================================
__global__ __launch_bounds__(256) void fc_kernel(const float* __restrict__ feat,
                                                 const float* __restrict__ w,
                                                 const float* __restrict__ b,
                                                 float* __restrict__ out) {
    const int j   = blockIdx.x;
    const int tid = threadIdx.x;
    const float* __restrict__ wr = w + (size_t)j * NCELL;
    float acc = 0.f;
    for (int k = tid; k < NCELL; k += 256) {
        float f = feat[k];
        f = (f > 0.f) ? f : 0.01f * f;
        acc += f * wr[k];
    }
#pragma unroll
    for (int off = 32; off > 0; off >>= 1) acc += __shfl_down(acc, off, 64);
    __shared__ float red[4];
    const int wv = tid >> 6, ln = tid & 63;
    if (ln == 0) red[wv] = acc;
    __syncthreads();
    if (tid == 0) {
        const float a = red[0] + red[1] + red[2] + red[3] + b[j];
        out[j] = fastrcp(1.0f + __expf(-a));
    }
}

extern "C" void kernel_launch(void* const* d_in, const int* in_sizes, int n_in,
                              void* d_out, int out_size, void* d_ws, size_t ws_size,
                              hipStream_t stream) {
    const float* s   = (const float*)d_in[0];
    const float* w0  = (const float*)d_in[1];
    const float* b0  = (const float*)d_in[2];
    const float* w1  = (const float*)d_in[3];
    const float* b1  = (const float*)d_in[4];
    const float* fcw = (const float*)d_in[5];
    const float* fcb = (const float*)d_in[6];
    float* out  = (float*)d_out;
    float* feat = (float*)d_ws;  // 2000 floats

    const size_t zx_bytes = (size_t)TSTEPS * NGATE * NCELL * sizeof(float);
    if (ws_size >= zx_bytes + 8192) {
        float* zx = (float*)((char*)d_ws + 8192);
        zx_prepass<<<TSTEPS, 256, 0, stream>>>(s, w0, b0, zx);
        convlstm_scan2<<<1, NTHR, 0, stream>>>(zx, w0, w1, b1, feat);
    } else {
        convlstm_scan<<<1, NTHR, 0, stream>>>(s, w0, b0, w1, b1, feat);
    }
    fc_kernel<<<NCELL, 256, 0, stream>>>(feat, fcw, fcb, out);
}

// Round 3
// 11878.867 us; speedup vs baseline: 1.9724x; 1.5543x over previous
//
#include <hip/hip_runtime.h>
#include <cstddef>

#define TSTEPS 4096
#define INLEN  1910
#define NROW   40
#define NCOL   50
#define NCELL  2000
#define NGATE  4
#define NTHR   512

// padded field dims for the pre-pass
#define PPH 42
#define PPW 52

typedef float f2 __attribute__((ext_vector_type(2)));
typedef float f4 __attribute__((ext_vector_type(4)));

// ---------- math helpers ----------
__device__ __forceinline__ float fastrcp(float x) { return __builtin_amdgcn_rcpf(x); }
__device__ __forceinline__ float sigm(float x)    { return fastrcp(1.0f + __expf(-x)); }
// overflow-safe tanh: 2*sigmoid(2x)-1
__device__ __forceinline__ float tanh_f(float x)  { return 2.0f * fastrcp(1.0f + __expf(-2.0f * x)) - 1.0f; }

// ---------- DPP full-wave lane shifts (zero fill at wave ends) ----------
__device__ __forceinline__ float lane_left(float x) {   // lane i <- lane i-1 (col c-1); lane0 -> 0
    int r = __builtin_amdgcn_update_dpp(0, __builtin_bit_cast(int, x),
                                        0x138 /*WAVE_SHR1*/, 0xF, 0xF, true);
    return __builtin_bit_cast(float, r);
}
__device__ __forceinline__ float lane_right(float x) {  // lane i <- lane i+1 (col c+1); lane63 -> 0
    int r = __builtin_amdgcn_update_dpp(0, __builtin_bit_cast(int, x),
                                        0x130 /*WAVE_SHL1*/, 0xF, 0xF, true);
    return __builtin_bit_cast(float, r);
}

// ---------- packed fp32 FMA (VOP3P): acc.{x,y} += w.{x,y} * v.{x,y} ----------
__device__ __forceinline__ void pkfma(f2 &acc, f2 w, f2 v) {
    asm("v_pk_fma_f32 %0, %1, %2, %0" : "+v"(acc) : "v"(w), "v"(v));
}
__device__ __forceinline__ f2 pkfma3(f2 w, f2 v, f2 a) {  // d = w*v + a
    f2 d;
    asm("v_pk_fma_f32 %0, %1, %2, %3" : "=v"(d) : "v"(w), "v"(v), "v"(a));
    return d;
}
__device__ __forceinline__ f2 dup(float v) { f2 r; r.x = v; r.y = v; return r; }

// ============================================================================
// Pre-pass: zx[t][cell][g] (float4 per cell) = b0[g] + conv2d_x(x[t])
// ============================================================================
__global__ __launch_bounds__(256) void zx_prepass4(const float* __restrict__ s,
                                                   const float* __restrict__ w0,
                                                   const float* __restrict__ b0,
                                                   float* __restrict__ zx) {
    __shared__ float xf[PPH * PPW];
    const int t = blockIdx.x;
    const int tid = threadIdx.x;
    for (int i = tid; i < PPH * PPW; i += 256) xf[i] = 0.f;
    __syncthreads();
    const float* __restrict__ xs = s + (size_t)t * INLEN;
    for (int j = tid; j < INLEN; j += 256) {
        const int r = j / NCOL, c = j % NCOL;
        xf[(r + 1) * PPW + (c + 1)] = xs[j];
    }
    float wg[4][9], bb[4];
#pragma unroll
    for (int g = 0; g < 4; ++g) {
        bb[g] = b0[g];
#pragma unroll
        for (int k = 0; k < 9; ++k) wg[g][k] = w0[(g * 2 + 0) * 9 + k];
    }
    __syncthreads();
    f4* __restrict__ zt = (f4*)zx + (size_t)t * NCELL;
    for (int cell = tid; cell < NCELL; cell += 256) {
        const int r = cell / NCOL, c = cell % NCOL;
        const int p = (r + 1) * PPW + (c + 1);
        float z0 = bb[0], z1 = bb[1], z2 = bb[2], z3 = bb[3];
#pragma unroll
        for (int ky = 0; ky < 3; ++ky)
#pragma unroll
            for (int kx = 0; kx < 3; ++kx) {
                const float v = xf[p + (ky - 1) * PPW + (kx - 1)];
                const int k = ky * 3 + kx;
                z0 += wg[0][k] * v; z1 += wg[1][k] * v;
                z2 += wg[2][k] * v; z3 += wg[3][k] * v;
            }
        zt[cell] = (f4){z0, z1, z2, z3};
    }
}

// ============================================================================
// Scan: 1 workgroup, lane=col, wave w owns rows 5w..5w+4. Packed gate-pairs.
// ============================================================================
__global__ __launch_bounds__(NTHR, 2) void convlstm_scan3(
        const float* __restrict__ zx,
        const float* __restrict__ w0g,
        const float* __restrict__ w1g, const float* __restrict__ b1g,
        float* __restrict__ feat) {
    __shared__ float hb0[2][8][2][64];   // [parity][wave][0=row 5w,1=row 5w+4][col]
    __shared__ float hb1[2][8][2][64];

    const int tid = threadIdx.x;
    const int w = tid >> 6;
    const int c = tid & 63;
    const float maskf = (c < NCOL) ? 1.f : 0.f;
    const int cmin = (c < NCOL) ? c : (NCOL - 1);

    hb0[0][w][0][c] = 0.f; hb0[0][w][1][c] = 0.f;
    hb0[1][w][0][c] = 0.f; hb0[1][w][1][c] = 0.f;
    hb1[0][w][0][c] = 0.f; hb1[0][w][1][c] = 0.f;
    hb1[1][w][0][c] = 0.f; hb1[1][w][1][c] = 0.f;

    // weight gate-pairs: a = gates {i,f}, b = gates {o,g}
    f2 Wh0a[9], Wh0b[9], Wx1a[9], Wx1b[9], Wh1a[9], Wh1b[9];
#pragma unroll
    for (int k = 0; k < 9; ++k) {
        Wh0a[k] = (f2){w0g[ 9 + k], w0g[27 + k]};
        Wh0b[k] = (f2){w0g[45 + k], w0g[63 + k]};
        Wx1a[k] = (f2){w1g[ 0 + k], w1g[18 + k]};
        Wx1b[k] = (f2){w1g[36 + k], w1g[54 + k]};
        Wh1a[k] = (f2){w1g[ 9 + k], w1g[27 + k]};
        Wh1b[k] = (f2){w1g[45 + k], w1g[63 + k]};
    }
    const f2 B1a = (f2){b1g[0], b1g[1]};
    const f2 B1b = (f2){b1g[2], b1g[3]};

    float h0[5] = {0,0,0,0,0}, c0[5] = {0,0,0,0,0};
    float h1[5] = {0,0,0,0,0}, c1[5] = {0,0,0,0,0};

    // zx addressing: lane base + 32-bit step offset, imm offsets per cell
    const char* __restrict__ zb = (const char*)zx;
    int voff = ((w * 5) * NCOL + cmin) * 16;

    f2 zA[5], zB[5];   // gate pairs {i,f} and {o,g}, accumulate conv in-place
    {
        const char* p = zb + voff;
#pragma unroll
        for (int i = 0; i < 5; ++i) {
            zA[i] = *(const f2*)(p + i * 800);
            zB[i] = *(const f2*)(p + i * 800 + 8);
        }
    }
    voff += 32000;   // -> t=1

    __syncthreads();

    for (int t = 0; t < TSTEPS; ++t) {
        const int pr_ = t & 1, pn = pr_ ^ 1;

        // old-state halos (written at end of t-1 into buffer pr_)
        const float h0t = (w > 0) ? hb0[pr_][w - 1][1][c] : 0.f;
        const float h0b = (w < 7) ? hb0[pr_][w + 1][0][c] : 0.f;
        const float h1t = (w > 0) ? hb1[pr_][w - 1][1][c] : 0.f;
        const float h1b = (w < 7) ? hb1[pr_][w + 1][0][c] : 0.f;

        // ---- phase 1: layer0 h-conv into zA/zB (in-place on loaded zx) ----
        {
            const float e[7] = {h0t, h0[0], h0[1], h0[2], h0[3], h0[4], h0b};
            f2 E[7], L[7], R[7];
#pragma unroll
            for (int r = 0; r < 7; ++r) {
                L[r] = dup(lane_left(e[r]));
                R[r] = dup(lane_right(e[r]));
                E[r] = dup(e[r]);
            }
#pragma unroll
            for (int i = 0; i < 5; ++i)
#pragma unroll
                for (int p = 0; p < 3; ++p) {
                    const int rr = i + p, k = p * 3;
                    pkfma(zA[i], Wh0a[k],   L[rr]);
                    pkfma(zA[i], Wh0a[k+1], E[rr]);
                    pkfma(zA[i], Wh0a[k+2], R[rr]);
                    pkfma(zB[i], Wh0b[k],   L[rr]);
                    pkfma(zB[i], Wh0b[k+1], E[rr]);
                    pkfma(zB[i], Wh0b[k+2], R[rr]);
                }
        }

        // ---- phase 2: layer1 h-part (independent of phase 1/3 -> overlaps trans) ----
        f2 uA[5], uB[5];
        {
            const float e[7] = {h1t, h1[0], h1[1], h1[2], h1[3], h1[4], h1b};
            f2 E[7], L[7], R[7];
#pragma unroll
            for (int r = 0; r < 7; ++r) {
                L[r] = dup(lane_left(e[r]));
                R[r] = dup(lane_right(e[r]));
                E[r] = dup(e[r]);
            }
#pragma unroll
            for (int i = 0; i < 5; ++i) {
                uA[i] = pkfma3(Wh1a[0], L[i], B1a);
                uB[i] = pkfma3(Wh1b[0], L[i], B1b);
                pkfma(uA[i], Wh1a[1], E[i]); pkfma(uA[i], Wh1a[2], R[i]);
                pkfma(uB[i], Wh1b[1], E[i]); pkfma(uB[i], Wh1b[2], R[i]);
#pragma unroll
                for (int p = 1; p < 3; ++p) {
                    const int rr = i + p, k = p * 3;
                    pkfma(uA[i], Wh1a[k],   L[rr]);
                    pkfma(uA[i], Wh1a[k+1], E[rr]);
                    pkfma(uA[i], Wh1a[k+2], R[rr]);
                    pkfma(uB[i], Wh1b[k],   L[rr]);
                    pkfma(uB[i], Wh1b[k+1], E[rr]);
                    pkfma(uB[i], Wh1b[k+2], R[rr]);
                }
            }
        }

        // ---- phase 3: layer0 gates ----
        float h0n[5];
#pragma unroll
        for (int i = 0; i < 5; ++i) {
            const float si = sigm(zA[i].x);
            const float sf = sigm(zA[i].y);
            const float so = sigm(zB[i].x);
            const float tg = tanh_f(zB[i].y);
            const float cn = sf * c0[i] + si * tg;
            c0[i] = cn;
            h0n[i] = so * tanh_f(cn) * maskf;
        }
        hb0[pn][w][0][c] = h0n[0];
        hb0[pn][w][1][c] = h0n[4];

        // prefetch zx(t+1) into the (now dead) zA/zB regs
        {
            const char* p = zb + voff;
#pragma unroll
            for (int i = 0; i < 5; ++i) {
                zA[i] = *(const f2*)(p + i * 800);
                zB[i] = *(const f2*)(p + i * 800 + 8);
            }
            if (t + 2 < TSTEPS) voff += 32000;
        }

        __syncthreads();   // B1: h0n halos visible

        const float h0nt = (w > 0) ? hb0[pn][w - 1][1][c] : 0.f;
        const float h0nb = (w < 7) ? hb0[pn][w + 1][0][c] : 0.f;

        // ---- phase 4: layer1 x-conv on h0n ----
        {
            const float e[7] = {h0nt, h0n[0], h0n[1], h0n[2], h0n[3], h0n[4], h0nb};
            f2 E[7], L[7], R[7];
#pragma unroll
            for (int r = 0; r < 7; ++r) {
                L[r] = dup(lane_left(e[r]));
                R[r] = dup(lane_right(e[r]));
                E[r] = dup(e[r]);
            }
#pragma unroll
            for (int i = 0; i < 5; ++i)
#pragma unroll
                for (int p = 0; p < 3; ++p) {
                    const int rr = i + p, k = p * 3;
                    pkfma(uA[i], Wx1a[k],   L[rr]);
                    pkfma(uA[i], Wx1a[k+1], E[rr]);
                    pkfma(uA[i], Wx1a[k+2], R[rr]);
                    pkfma(uB[i], Wx1b[k],   L[rr]);
                    pkfma(uB[i], Wx1b[k+1], E[rr]);
                    pkfma(uB[i], Wx1b[k+2], R[rr]);
                }
        }

        // ---- phase 5: layer1 gates ----
#pragma unroll
        for (int i = 0; i < 5; ++i) {
            const float si = sigm(uA[i].x);
            const float sf = sigm(uA[i].y);
            const float so = sigm(uB[i].x);
            const float tg = tanh_f(uB[i].y);
            const float cn = sf * c1[i] + si * tg;
            c1[i] = cn;
            h1[i] = so * tanh_f(cn) * maskf;
        }
        hb1[pn][w][0][c] = h1[0];
        hb1[pn][w][1][c] = h1[4];

#pragma unroll
        for (int i = 0; i < 5; ++i) h0[i] = h0n[i];

        __syncthreads();   // B2: h1 halos + parity flip visible
    }

    if (c < NCOL) {
#pragma unroll
        for (int i = 0; i < 5; ++i)
            feat[(w * 5 + i) * NCOL + c] = h1[i];
    }
}

// ============================================================================
// Fallback monolithic scan (round-1, known-correct; used only if ws too small)
// ============================================================================
#define PW 52
#define PH 42
__device__ __forceinline__ void cell_update(const float* __restrict__ xf,
                                            const float* __restrict__ hf,
                                            const float (&wr)[72], const float (&br)[4],
                                            const int (&pidx)[4],
                                            float (&cst)[4], float (&hn)[4]) {
#pragma unroll
    for (int q = 0; q < 4; ++q) {
        const int p = pidx[q];
        float z0 = br[0], z1 = br[1], z2 = br[2], z3 = br[3];
#pragma unroll
        for (int ky = 0; ky < 3; ++ky)
#pragma unroll
            for (int kx = 0; kx < 3; ++kx) {
                const int off = (ky - 1) * PW + (kx - 1);
                const float xval = xf[p + off];
                const float hval = hf[p + off];
                const int wi = ky * 3 + kx;
                z0 += wr[ 0 + wi] * xval + wr[ 9 + wi] * hval;
                z1 += wr[18 + wi] * xval + wr[27 + wi] * hval;
                z2 += wr[36 + wi] * xval + wr[45 + wi] * hval;
                z3 += wr[54 + wi] * xval + wr[63 + wi] * hval;
            }
        const float ig = sigm(z0), fg = sigm(z1), og = sigm(z2), gg = tanh_f(z3);
        const float cn = fg * cst[q] + ig * gg;
        cst[q] = cn;
        hn[q]  = og * tanh_f(cn);
    }
}

__global__ __launch_bounds__(NTHR, 2) void convlstm_scan(
    const float* __restrict__ s,
    const float* __restrict__ w0g, const float* __restrict__ b0g,
    const float* __restrict__ w1g, const float* __restrict__ b1g,
    float* __restrict__ feat) {
    __shared__ float xb[PH * PW];
    __shared__ float h0[PH * PW];
    __shared__ float h1[PH * PW];
    const int tid = threadIdx.x;
    for (int i = tid; i < PH * PW; i += NTHR) { xb[i] = 0.f; h0[i] = 0.f; h1[i] = 0.f; }
    float w0r[72], w1r[72], b0r[4], b1r[4];
#pragma unroll
    for (int i = 0; i < 72; ++i) w0r[i] = w0g[i];
#pragma unroll
    for (int i = 0; i < 72; ++i) w1r[i] = w1g[i];
#pragma unroll
    for (int i = 0; i < 4; ++i) { b0r[i] = b0g[i]; b1r[i] = b1g[i]; }
    int pidx[4]; bool cv[4];
#pragma unroll
    for (int q = 0; q < 4; ++q) {
        int cell = tid + q * NTHR;
        cv[q] = (cell < NCELL);
        if (!cv[q]) cell = 0;
        const int r = cell / NCOL, c = cell % NCOL;
        pidx[q] = (r + 1) * PW + (c + 1);
    }
    int xjj[4], xpp[4]; bool xv[4];
#pragma unroll
    for (int k = 0; k < 4; ++k) {
        int j = tid + k * NTHR;
        xv[k] = (j < INLEN);
        if (!xv[k]) j = 0;
        xjj[k] = j;
        const int r = j / NCOL, c = j % NCOL;
        xpp[k] = (r + 1) * PW + (c + 1);
    }
    float c0r[4] = {0,0,0,0}, c1r[4] = {0,0,0,0};
    float xr[4];
#pragma unroll
    for (int k = 0; k < 4; ++k) xr[k] = xv[k] ? s[xjj[k]] : 0.f;
    __syncthreads();
    for (int t = 0; t < TSTEPS; ++t) {
#pragma unroll
        for (int k = 0; k < 4; ++k)
            if (xv[k]) xb[xpp[k]] = xr[k];
        {
            const size_t bofs = (size_t)(t + 1 < TSTEPS ? t + 1 : t) * INLEN;
#pragma unroll
            for (int k = 0; k < 4; ++k) xr[k] = xv[k] ? s[bofs + xjj[k]] : 0.f;
        }
        __syncthreads();
        float hn0[4];
        cell_update(xb, h0, w0r, b0r, pidx, c0r, hn0);
        __syncthreads();
#pragma unroll
        for (int q = 0; q < 4; ++q)
            if (cv[q]) h0[pidx[q]] = hn0[q];
        __syncthreads();
        float hn1[4];
        cell_update(h0, h1, w1r, b1r, pidx, c1r, hn1);
        __syncthreads();
#pragma unroll
        for (int q = 0; q < 4; ++q)
            if (cv[q]) h1[pidx[q]] = hn1[q];
    }
#pragma unroll
    for (int q = 0; q < 4; ++q)
        if (cv[q]) feat[tid + q * NTHR] = h1[pidx[q]];
}

// ============================================================================
// FC epilogue
// ============================================================================
__global__ __launch_bounds__(256) void fc_kernel(const float* __restrict__ feat,
                                                 const float* __restrict__ w,
                                                 const float* __restrict__ b,
                                                 float* __restrict__ out) {
    const int j   = blockIdx.x;
    const int tid = threadIdx.x;
    const float* __restrict__ wr = w + (size_t)j * NCELL;
    float acc = 0.f;
    for (int k = tid; k < NCELL; k += 256) {
        float f = feat[k];
        f = (f > 0.f) ? f : 0.01f * f;
        acc += f * wr[k];
    }
#pragma unroll
    for (int off = 32; off > 0; off >>= 1) acc += __shfl_down(acc, off, 64);
    __shared__ float red[4];
    const int wv = tid >> 6, ln = tid & 63;
    if (ln == 0) red[wv] = acc;
    __syncthreads();
    if (tid == 0) {
        const float a = red[0] + red[1] + red[2] + red[3] + b[j];
        out[j] = fastrcp(1.0f + __expf(-a));
    }
}

extern "C" void kernel_launch(void* const* d_in, const int* in_sizes, int n_in,
                              void* d_out, int out_size, void* d_ws, size_t ws_size,
                              hipStream_t stream) {
    const float* s   = (const float*)d_in[0];
    const float* w0  = (const float*)d_in[1];
    const float* b0  = (const float*)d_in[2];
    const float* w1  = (const float*)d_in[3];
    const float* b1  = (const float*)d_in[4];
    const float* fcw = (const float*)d_in[5];
    const float* fcb = (const float*)d_in[6];
    float* out  = (float*)d_out;
    float* feat = (float*)d_ws;   // 2000 floats

    const size_t zx_bytes = (size_t)TSTEPS * NCELL * 4 * sizeof(float);
    if (ws_size >= zx_bytes + 8192) {
        float* zx = (float*)((char*)d_ws + 8192);
        zx_prepass4<<<TSTEPS, 256, 0, stream>>>(s, w0, b0, zx);
        convlstm_scan3<<<1, NTHR, 0, stream>>>(zx, w0, w1, b1, feat);
    } else {
        convlstm_scan<<<1, NTHR, 0, stream>>>(s, w0, b0, w1, b1, feat);
    }
    fc_kernel<<<NCELL, 256, 0, stream>>>(feat, fcw, fcb, out);
}

// Round 5
// 9756.171 us; speedup vs baseline: 2.4016x; 1.2176x over previous
//
#include <hip/hip_runtime.h>
#include <cstddef>

#define TSTEPS 4096
#define INLEN  1910
#define NROW   40
#define NCOL   50
#define NCELL  2000
#define NTHR   512

// padded field dims for the pre-pass
#define PPH 42
#define PPW 52

typedef float f2 __attribute__((ext_vector_type(2)));
typedef float f4 __attribute__((ext_vector_type(4)));

#define L2E  1.4426950408889634f
#define SGK  (-2.f * L2E)          // scale applied to tanh() args

// ---------- math helpers ----------
__device__ __forceinline__ float fastrcp(float x)  { return __builtin_amdgcn_rcpf(x); }
__device__ __forceinline__ float fastexp2(float x) { return __builtin_amdgcn_exp2f(x); }
// arg pre-scaled by -log2(e): sigmoid(z) = 1/(1+2^(z'))
__device__ __forceinline__ float sigm_n(float zp) { return fastrcp(1.f + fastexp2(zp)); }
// arg pre-scaled by -2*log2(e): tanh(z) = 2/(1+2^(z')) - 1
__device__ __forceinline__ float tanh_n(float zp) { return 2.f * fastrcp(1.f + fastexp2(zp)) - 1.f; }
// legacy (fallback kernel only)
__device__ __forceinline__ float sigm(float x)   { return fastrcp(1.0f + __expf(-x)); }
__device__ __forceinline__ float tanh_f(float x) { return 2.0f * fastrcp(1.0f + __expf(-2.0f * x)) - 1.0f; }

// ---------- DPP full-wave lane shifts (zero fill at wave ends) ----------
__device__ __forceinline__ float lane_left(float x) {   // lane i <- lane i-1; lane0 -> 0
    int r = __builtin_amdgcn_update_dpp(0, __builtin_bit_cast(int, x),
                                        0x138 /*WAVE_SHR1*/, 0xF, 0xF, true);
    return __builtin_bit_cast(float, r);
}
__device__ __forceinline__ float lane_right(float x) {  // lane i <- lane i+1; lane63 -> 0
    int r = __builtin_amdgcn_update_dpp(0, __builtin_bit_cast(int, x),
                                        0x130 /*WAVE_SHL1*/, 0xF, 0xF, true);
    return __builtin_bit_cast(float, r);
}

// packed fp32 FMA, src1 broadcast from its lo half (op_sel_hi[src1]=0):
//   acc.lo += w.lo * v.lo ; acc.hi += w.hi * v.lo
__device__ __forceinline__ void pkfma_b(f2 &acc, f2 w, f2 vlo) {
    asm("v_pk_fma_f32 %0, %1, %2, %0 op_sel_hi:[1,0,1]" : "+v"(acc) : "v"(w), "v"(vlo));
}

// 3x3 conv over 7 stencil rows -> 5 output rows, gate-pairs A/B accumulated.
// Row-wise: only one (L,E,R) value triple live at a time (register pressure).
__device__ __forceinline__ void conv5(const float (&e)[7], const f2 (&Wa)[9], const f2 (&Wb)[9],
                                      f2 (&aA)[5], f2 (&aB)[5]) {
#pragma unroll
    for (int rr = 0; rr < 7; ++rr) {
        f2 Lv, Ev, Rv;                 // hi halves intentionally unused (broadcast reads lo)
        Lv.x = lane_left(e[rr]);
        Ev.x = e[rr];
        Rv.x = lane_right(e[rr]);
        const int ilo = (rr - 2 > 0) ? (rr - 2) : 0;
        const int ihi = (rr < 4) ? rr : 4;
#pragma unroll
        for (int i = ilo; i <= ihi; ++i) {
            const int k = (rr - i) * 3;
            pkfma_b(aA[i], Wa[k],     Lv);
            pkfma_b(aA[i], Wa[k + 1], Ev);
            pkfma_b(aA[i], Wa[k + 2], Rv);
            pkfma_b(aB[i], Wb[k],     Lv);
            pkfma_b(aB[i], Wb[k + 1], Ev);
            pkfma_b(aB[i], Wb[k + 2], Rv);
        }
    }
}

// ============================================================================
// Pre-pass: zx[t][cell] = f4{i,f,o,g} pre-activations of layer-0 x-conv,
// PRE-SCALED by {-L2E,-L2E,-L2E,-2*L2E} for exp2-domain gates.
// ============================================================================
__global__ __launch_bounds__(256) void zx_prepass4(const float* __restrict__ s,
                                                   const float* __restrict__ w0,
                                                   const float* __restrict__ b0,
                                                   float* __restrict__ zx) {
    __shared__ float xf[PPH * PPW];
    const int t = blockIdx.x;
    const int tid = threadIdx.x;
    for (int i = tid; i < PPH * PPW; i += 256) xf[i] = 0.f;
    __syncthreads();
    const float* __restrict__ xs = s + (size_t)t * INLEN;
    for (int j = tid; j < INLEN; j += 256) {
        const int r = j / NCOL, c = j % NCOL;
        xf[(r + 1) * PPW + (c + 1)] = xs[j];
    }
    const float SC[4] = {-L2E, -L2E, -L2E, SGK};
    float wg[4][9], bb[4];
#pragma unroll
    for (int g = 0; g < 4; ++g) {
        bb[g] = b0[g] * SC[g];
#pragma unroll
        for (int k = 0; k < 9; ++k) wg[g][k] = w0[(g * 2 + 0) * 9 + k] * SC[g];
    }
    __syncthreads();
    f4* __restrict__ zt = (f4*)zx + (size_t)t * NCELL;
    for (int cell = tid; cell < NCELL; cell += 256) {
        const int r = cell / NCOL, c = cell % NCOL;
        const int p = (r + 1) * PPW + (c + 1);
        float z0 = bb[0], z1 = bb[1], z2 = bb[2], z3 = bb[3];
#pragma unroll
        for (int ky = 0; ky < 3; ++ky)
#pragma unroll
            for (int kx = 0; kx < 3; ++kx) {
                const float v = xf[p + (ky - 1) * PPW + (kx - 1)];
                const int k = ky * 3 + kx;
                z0 += wg[0][k] * v; z1 += wg[1][k] * v;
                z2 += wg[2][k] * v; z3 += wg[3][k] * v;
            }
        zt[cell] = (f4){z0, z1, z2, z3};
    }
}

// ============================================================================
// Scan: 1 workgroup, lane=col, wave w owns rows 5w..5w+4.
// ONE barrier per step; padded-halo LDS (rows 0/9 stay zero); weights pinned
// in VGPRs; op_sel broadcast pkfma; exp2-domain gates.
// ============================================================================
__global__ __launch_bounds__(NTHR, 2) void convlstm_scan4(
        const float* __restrict__ zx,
        const float* __restrict__ w0g,
        const float* __restrict__ w1g, const float* __restrict__ b1g,
        float* __restrict__ feat) {
    // [parity][padded wave-row 0..9][0=row 5w, 1=row 5w+4][col]
    __shared__ float P0[2][10][2][64];
    __shared__ float P1[2][10][2][64];

    const int tid = threadIdx.x;
    const int w = tid >> 6;
    const int c = tid & 63;
    const float maskf = (c < NCOL) ? 1.f : 0.f;
    const int cmin = (c < NCOL) ? c : (NCOL - 1);

    // zero all of P0/P1 (incl. pad rows 0 and 9, which are never written again)
    {
        float* p0 = &P0[0][0][0][0];
        float* p1 = &P1[0][0][0][0];
        for (int i = tid; i < 2 * 10 * 2 * 64; i += NTHR) { p0[i] = 0.f; p1[i] = 0.f; }
    }

    // ---- weight gate-pairs, pre-scaled for exp2-domain gates ----
    const float SA = -L2E;
    f2 Wh0a[9], Wh0b[9], Wx1a[9], Wx1b[9], Wh1a[9], Wh1b[9];
#pragma unroll
    for (int k = 0; k < 9; ++k) {
        Wh0a[k] = (f2){w0g[ 9 + k] * SA, w0g[27 + k] * SA};
        Wh0b[k] = (f2){w0g[45 + k] * SA, w0g[63 + k] * SGK};
        Wx1a[k] = (f2){w1g[ 0 + k] * SA, w1g[18 + k] * SA};
        Wx1b[k] = (f2){w1g[36 + k] * SA, w1g[54 + k] * SGK};
        Wh1a[k] = (f2){w1g[ 9 + k] * SA, w1g[27 + k] * SA};
        Wh1b[k] = (f2){w1g[45 + k] * SA, w1g[63 + k] * SGK};
    }
    f2 B1a = (f2){b1g[0] * SA, b1g[1] * SA};
    f2 B1b = (f2){b1g[2] * SA, b1g[3] * SGK};
    // pin the pairs into VGPRs (prevent SGPR-remat -> per-use v_mov rebuilds)
#pragma unroll
    for (int k = 0; k < 9; ++k) {
        asm volatile("" : "+v"(Wh0a[k]), "+v"(Wh0b[k]), "+v"(Wx1a[k]),
                          "+v"(Wx1b[k]), "+v"(Wh1a[k]), "+v"(Wh1b[k]));
    }
    asm volatile("" : "+v"(B1a), "+v"(B1b));

    float h0[5] = {0,0,0,0,0}, c0[5] = {0,0,0,0,0};
    float h1[5] = {0,0,0,0,0}, c1[5] = {0,0,0,0,0};

    // zx addressing: per-lane base + 32-bit step offset; 5 dwordx4 w/ imm offsets
    const char* __restrict__ zb = (const char*)zx;
    int voff = ((w * 5) * NCOL + cmin) * 16;

    f2 zA[5], zB[5];   // {i,f} and {o,g}; conv accumulates in place
    {
        const char* p = zb + voff;
#pragma unroll
        for (int i = 0; i < 5; ++i) {
            const f4 z4 = *(const f4*)(p + i * 800);
            zA[i] = __builtin_shufflevector(z4, z4, 0, 1);
            zB[i] = __builtin_shufflevector(z4, z4, 2, 3);
        }
    }
    voff += 32000;

    __syncthreads();

    for (int t = 0; t < TSTEPS; ++t) {
        const int pn = t & 1, pr_ = pn ^ 1;

        // ================= phase A : layer 0 =================
        {
            float e0[7];
            e0[0] = P0[pr_][w][1][c];          // row 5w-1 (pad row -> 0 at w=0)
            e0[6] = P0[pr_][w + 2][0][c];      // row 5w+5
#pragma unroll
            for (int i = 0; i < 5; ++i) e0[i + 1] = h0[i];
            conv5(e0, Wh0a, Wh0b, zA, zB);
        }
#pragma unroll
        for (int i = 0; i < 5; ++i) {
            const float si = sigm_n(zA[i].x);
            const float sf = sigm_n(zA[i].y);
            const float so = sigm_n(zB[i].x);
            const float tg = tanh_n(zB[i].y);
            const float cn = sf * c0[i] + si * tg;
            c0[i] = cn;
            h0[i] = so * tanh_n(cn * SGK) * maskf;
        }
        P0[pn][w + 1][0][c] = h0[0];
        P0[pn][w + 1][1][c] = h0[4];

        // prefetch z(t+1) into the (now consumed) zA/zB
        {
            const char* p = zb + voff;
#pragma unroll
            for (int i = 0; i < 5; ++i) {
                const f4 z4 = *(const f4*)(p + i * 800);
                zA[i] = __builtin_shufflevector(z4, z4, 0, 1);
                zB[i] = __builtin_shufflevector(z4, z4, 2, 3);
            }
            if (t + 2 < TSTEPS) voff += 32000;
        }

        __syncthreads();   // the ONLY barrier per step

        // ================= phase B : layer 1 =================
        f2 uA[5], uB[5];
#pragma unroll
        for (int i = 0; i < 5; ++i) { uA[i] = B1a; uB[i] = B1b; }
        {
            float ex[7];
            ex[0] = P0[pn][w][1][c];           // new h0 halos
            ex[6] = P0[pn][w + 2][0][c];
#pragma unroll
            for (int i = 0; i < 5; ++i) ex[i + 1] = h0[i];
            conv5(ex, Wx1a, Wx1b, uA, uB);
        }
        {
            float eh[7];
            eh[0] = P1[pr_][w][1][c];          // old h1 halos
            eh[6] = P1[pr_][w + 2][0][c];
#pragma unroll
            for (int i = 0; i < 5; ++i) eh[i + 1] = h1[i];
            conv5(eh, Wh1a, Wh1b, uA, uB);
        }
#pragma unroll
        for (int i = 0; i < 5; ++i) {
            const float si = sigm_n(uA[i].x);
            const float sf = sigm_n(uA[i].y);
            const float so = sigm_n(uB[i].x);
            const float tg = tanh_n(uB[i].y);
            const float cn = sf * c1[i] + si * tg;
            c1[i] = cn;
            h1[i] = so * tanh_n(cn * SGK) * maskf;
        }
        P1[pn][w + 1][0][c] = h1[0];
        P1[pn][w + 1][1][c] = h1[4];
        // no trailing barrier: next step's phase A touches only P0[pr_], and the
        // next __syncthreads orders these P1 writes before their phase-B readers.
    }

    if (c < NCOL) {
#pragma unroll
        for (int i = 0; i < 5; ++i)
            feat[(w * 5 + i) * NCOL + c] = h1[i];
    }
}

// ============================================================================
// Fallback monolithic scan (round-1, known-correct; used only if ws too small)
// ============================================================================
#define PW 52
#define PH 42
__device__ __forceinline__ void cell_update(const float* __restrict__ xf,
                                            const float* __restrict__ hf,
                                            const float (&wr)[72], const float (&br)[4],
                                            const int (&pidx)[4],
                                            float (&cst)[4], float (&hn)[4]) {
#pragma unroll
    for (int q = 0; q < 4; ++q) {
        const int p = pidx[q];
        float z0 = br[0], z1 = br[1], z2 = br[2], z3 = br[3];
#pragma unroll
        for (int ky = 0; ky < 3; ++ky)
#pragma unroll
            for (int kx = 0; kx < 3; ++kx) {
                const int off = (ky - 1) * PW + (kx - 1);
                const float xval = xf[p + off];
                const float hval = hf[p + off];
                const int wi = ky * 3 + kx;
                z0 += wr[ 0 + wi] * xval + wr[ 9 + wi] * hval;
                z1 += wr[18 + wi] * xval + wr[27 + wi] * hval;
                z2 += wr[36 + wi] * xval + wr[45 + wi] * hval;
                z3 += wr[54 + wi] * xval + wr[63 + wi] * hval;
            }
        const float ig = sigm(z0), fg = sigm(z1), og = sigm(z2), gg = tanh_f(z3);
        const float cn = fg * cst[q] + ig * gg;
        cst[q] = cn;
        hn[q]  = og * tanh_f(cn);
    }
}

__global__ __launch_bounds__(NTHR, 2) void convlstm_scan(
    const float* __restrict__ s,
    const float* __restrict__ w0g, const float* __restrict__ b0g,
    const float* __restrict__ w1g, const float* __restrict__ b1g,
    float* __restrict__ feat) {
    __shared__ float xb[PH * PW];
    __shared__ float h0[PH * PW];
    __shared__ float h1[PH * PW];
    const int tid = threadIdx.x;
    for (int i = tid; i < PH * PW; i += NTHR) { xb[i] = 0.f; h0[i] = 0.f; h1[i] = 0.f; }
    float w0r[72], w1r[72], b0r[4], b1r[4];
#pragma unroll
    for (int i = 0; i < 72; ++i) w0r[i] = w0g[i];
#pragma unroll
    for (int i = 0; i < 72; ++i) w1r[i] = w1g[i];
#pragma unroll
    for (int i = 0; i < 4; ++i) { b0r[i] = b0g[i]; b1r[i] = b1g[i]; }
    int pidx[4]; bool cv[4];
#pragma unroll
    for (int q = 0; q < 4; ++q) {
        int cell = tid + q * NTHR;
        cv[q] = (cell < NCELL);
        if (!cv[q]) cell = 0;
        const int r = cell / NCOL, cc = cell % NCOL;
        pidx[q] = (r + 1) * PW + (cc + 1);
    }
    int xjj[4], xpp[4]; bool xv[4];
#pragma unroll
    for (int k = 0; k < 4; ++k) {
        int j = tid + k * NTHR;
        xv[k] = (j < INLEN);
        if (!xv[k]) j = 0;
        xjj[k] = j;
        const int r = j / NCOL, cc = j % NCOL;
        xpp[k] = (r + 1) * PW + (cc + 1);
    }
    float c0r[4] = {0,0,0,0}, c1r[4] = {0,0,0,0};
    float xr[4];
#pragma unroll
    for (int k = 0; k < 4; ++k) xr[k] = xv[k] ? s[xjj[k]] : 0.f;
    __syncthreads();
    for (int t = 0; t < TSTEPS; ++t) {
#pragma unroll
        for (int k = 0; k < 4; ++k)
            if (xv[k]) xb[xpp[k]] = xr[k];
        {
            const size_t bofs = (size_t)(t + 1 < TSTEPS ? t + 1 : t) * INLEN;
#pragma unroll
            for (int k = 0; k < 4; ++k) xr[k] = xv[k] ? s[bofs + xjj[k]] : 0.f;
        }
        __syncthreads();
        float hn0[4];
        cell_update(xb, h0, w0r, b0r, pidx, c0r, hn0);
        __syncthreads();
#pragma unroll
        for (int q = 0; q < 4; ++q)
            if (cv[q]) h0[pidx[q]] = hn0[q];
        __syncthreads();
        float hn1[4];
        cell_update(h0, h1, w1r, b1r, pidx, c1r, hn1);
        __syncthreads();
#pragma unroll
        for (int q = 0; q < 4; ++q)
            if (cv[q]) h1[pidx[q]] = hn1[q];
    }
#pragma unroll
    for (int q = 0; q < 4; ++q)
        if (cv[q]) feat[tid + q * NTHR] = h1[pidx[q]];
}

// ============================================================================
// FC epilogue
// ============================================================================
__global__ __launch_bounds__(256) void fc_kernel(const float* __restrict__ feat,
                                                 const float* __restrict__ w,
                                                 const float* __restrict__ b,
                                                 float* __restrict__ out) {
    const int j   = blockIdx.x;
    const int tid = threadIdx.x;
    const float* __restrict__ wr = w + (size_t)j * NCELL;
    float acc = 0.f;
    for (int k = tid; k < NCELL; k += 256) {
        float f = feat[k];
        f = (f > 0.f) ? f : 0.01f * f;
        acc += f * wr[k];
    }
#pragma unroll
    for (int off = 32; off > 0; off >>= 1) acc += __shfl_down(acc, off, 64);
    __shared__ float red[4];
    const int wv = tid >> 6, ln = tid & 63;
    if (ln == 0) red[wv] = acc;
    __syncthreads();
    if (tid == 0) {
        const float a = red[0] + red[1] + red[2] + red[3] + b[j];
        out[j] = fastrcp(1.0f + __expf(-a));
    }
}

extern "C" void kernel_launch(void* const* d_in, const int* in_sizes, int n_in,
                              void* d_out, int out_size, void* d_ws, size_t ws_size,
                              hipStream_t stream) {
    const float* s   = (const float*)d_in[0];
    const float* w0  = (const float*)d_in[1];
    const float* b0  = (const float*)d_in[2];
    const float* w1  = (const float*)d_in[3];
    const float* b1  = (const float*)d_in[4];
    const float* fcw = (const float*)d_in[5];
    const float* fcb = (const float*)d_in[6];
    float* out  = (float*)d_out;
    float* feat = (float*)d_ws;   // 2000 floats

    const size_t zx_bytes = (size_t)TSTEPS * NCELL * 4 * sizeof(float);
    if (ws_size >= zx_bytes + 8192) {
        float* zx = (float*)((char*)d_ws + 8192);
        zx_prepass4<<<TSTEPS, 256, 0, stream>>>(s, w0, b0, zx);
        convlstm_scan4<<<1, NTHR, 0, stream>>>(zx, w0, w1, b1, feat);
    } else {
        convlstm_scan<<<1, NTHR, 0, stream>>>(s, w0, b0, w1, b1, feat);
    }
    fc_kernel<<<NCELL, 256, 0, stream>>>(feat, fcw, fcb, out);
}

// Round 6
// 8864.404 us; speedup vs baseline: 2.6432x; 1.1006x over previous
//
#include <hip/hip_runtime.h>
#include <cstddef>

#define TSTEPS 4096
#define INLEN  1910
#define NROW   40
#define NCOL   50
#define NCELL  2000
#define NTHR   512

// padded field dims for the pre-pass
#define PPH 42
#define PPW 52

typedef float f2 __attribute__((ext_vector_type(2)));
typedef float f4 __attribute__((ext_vector_type(4)));
typedef long long i64;

#define L2E  1.4426950408889634f
#define SGK  (-2.f * L2E)          // scale applied to tanh() args (and c-state)

// ---------- math helpers ----------
__device__ __forceinline__ float fastrcp(float x)  { return __builtin_amdgcn_rcpf(x); }
__device__ __forceinline__ float fastexp2(float x) { return __builtin_amdgcn_exp2f(x); }
// legacy (fallback kernel + fc)
__device__ __forceinline__ float sigm(float x)   { return fastrcp(1.0f + __expf(-x)); }
__device__ __forceinline__ float tanh_f(float x) { return 2.0f * fastrcp(1.0f + __expf(-2.0f * x)) - 1.0f; }

// ---------- DPP full-wave lane shifts (zero fill at wave ends) ----------
__device__ __forceinline__ float lane_left(float x) {   // lane i <- lane i-1; lane0 -> 0
    int r = __builtin_amdgcn_update_dpp(0, __builtin_bit_cast(int, x),
                                        0x138 /*WAVE_SHR1*/, 0xF, 0xF, true);
    return __builtin_bit_cast(float, r);
}
__device__ __forceinline__ float lane_right(float x) {  // lane i <- lane i+1; lane63 -> 0
    int r = __builtin_amdgcn_update_dpp(0, __builtin_bit_cast(int, x),
                                        0x130 /*WAVE_SHL1*/, 0xF, 0xF, true);
    return __builtin_bit_cast(float, r);
}

// packed fp32 FMA, src1 broadcast from its lo half (op_sel_hi[src1]=0)
// VGPR-weight form: acc.{lo,hi} += w.{lo,hi} * v.lo
__device__ __forceinline__ void pkfma_v(f2 &acc, f2 w, f2 vlo) {
    asm("v_pk_fma_f32 %0, %1, %2, %0 op_sel_hi:[1,0,1]" : "+v"(acc) : "v"(w), "v"(vlo));
}
// SGPR-pair-weight form (1 scalar read per VALU instr is legal)
__device__ __forceinline__ void pkfma_s(f2 &acc, i64 w, f2 vlo) {
    asm("v_pk_fma_f32 %0, %1, %2, %0 op_sel_hi:[1,0,1]" : "+v"(acc) : "s"(w), "v"(vlo));
}
// init form: d = w(s).{lo,hi} * v.lo + B(v).{lo,hi}
__device__ __forceinline__ f2 pkfma3_s(i64 w, f2 vlo, f2 B) {
    f2 d;
    asm("v_pk_fma_f32 %0, %1, %2, %3 op_sel_hi:[1,0,1]" : "=v"(d) : "s"(w), "v"(vlo), "v"(B));
    return d;
}

// pack two uniform floats into an SGPR pair
__device__ __forceinline__ i64 mk_sw(float lo, float hi) {
    int l = __builtin_amdgcn_readfirstlane(__builtin_bit_cast(int, lo));
    int h = __builtin_amdgcn_readfirstlane(__builtin_bit_cast(int, hi));
    return (i64)((unsigned long long)(unsigned)l | ((unsigned long long)(unsigned)h << 32));
}

// 3x3 conv over 7 stencil rows -> 5 output rows; VGPR weights
__device__ __forceinline__ void conv5_v(const float (&e)[7], const f2 (&Wa)[9], const f2 (&Wb)[9],
                                        f2 (&aA)[5], f2 (&aB)[5]) {
#pragma unroll
    for (int rr = 0; rr < 7; ++rr) {
        f2 Lv, Ev, Rv;                 // hi halves unused (op_sel broadcast reads lo)
        Lv.x = lane_left(e[rr]);
        Ev.x = e[rr];
        Rv.x = lane_right(e[rr]);
        const int ilo = (rr - 2 > 0) ? (rr - 2) : 0;
        const int ihi = (rr < 4) ? rr : 4;
#pragma unroll
        for (int i = ilo; i <= ihi; ++i) {
            const int k = (rr - i) * 3;
            pkfma_v(aA[i], Wa[k],     Lv);
            pkfma_v(aA[i], Wa[k + 1], Ev);
            pkfma_v(aA[i], Wa[k + 2], Rv);
            pkfma_v(aB[i], Wb[k],     Lv);
            pkfma_v(aB[i], Wb[k + 1], Ev);
            pkfma_v(aB[i], Wb[k + 2], Rv);
        }
    }
}

// SGPR-weight conv; INIT=true initializes acc i at its first tap with bias B
template<bool INIT>
__device__ __forceinline__ void conv5_s(const float (&e)[7], const i64 (&Wa)[9], const i64 (&Wb)[9],
                                        f2 (&aA)[5], f2 (&aB)[5], f2 Ba, f2 Bb) {
#pragma unroll
    for (int rr = 0; rr < 7; ++rr) {
        f2 Lv, Ev, Rv;
        Lv.x = lane_left(e[rr]);
        Ev.x = e[rr];
        Rv.x = lane_right(e[rr]);
        const int ilo = (rr - 2 > 0) ? (rr - 2) : 0;
        const int ihi = (rr < 4) ? rr : 4;
#pragma unroll
        for (int i = ilo; i <= ihi; ++i) {
            const int k = (rr - i) * 3;
            if (INIT && rr == i) {     // first touch of acc i
                aA[i] = pkfma3_s(Wa[k], Lv, Ba);
                aB[i] = pkfma3_s(Wb[k], Lv, Bb);
            } else {
                pkfma_s(aA[i], Wa[k], Lv);
                pkfma_s(aB[i], Wb[k], Lv);
            }
            pkfma_s(aA[i], Wa[k + 1], Ev);
            pkfma_s(aA[i], Wa[k + 2], Rv);
            pkfma_s(aB[i], Wb[k + 1], Ev);
            pkfma_s(aB[i], Wb[k + 2], Rv);
        }
    }
}

// Fused LSTM gate update, 7 transcendentals (5 exp2 + 2 rcp).
// zA={i',f'}, zB={o',g'} pre-scaled by -L2E (i,f,o) / SGK (g).
// c-state cs is stored PRE-SCALED by SGK (cs = SGK*c). Returns h (masked).
__device__ __forceinline__ float gates_update(f2 zA, f2 zB, float &cs, float maskf, float sgkv) {
    const float ea = fastexp2(zA.x);           // e^-i
    const float eb = fastexp2(zA.y);           // e^-f
    const float ec = fastexp2(zB.x);           // e^-o
    const float ed = fastexp2(zB.y);           // e^-2g
    const float Q  = 1.f + eb;
    const float P1 = (1.f + ea) * (1.f + ed);
    const float r1 = fastrcp(Q * P1);
    const float sf = P1 * r1;                  // sigmoid(f)
    const float nm = ed * (2.f * L2E) + sgkv;  // SGK*(1-ed)
    const float sitgS = Q * nm * r1;           // SGK * sigmoid(i)*tanh(g)
    cs = sf * cs + sitgS;                      // SGK * c_new
    const float ee = fastexp2(cs);             // e^-2c
    const float r2 = fastrcp((1.f + ec) * (1.f + ee));
    return (1.f - ee) * r2 * maskf;            // sigmoid(o)*tanh(c)
}

// ============================================================================
// Pre-pass: zx[t][cell] = f4{i,f,o,g} pre-activations of layer-0 x-conv,
// PRE-SCALED by {-L2E,-L2E,-L2E,SGK} for exp2-domain gates.
// ============================================================================
__global__ __launch_bounds__(256) void zx_prepass4(const float* __restrict__ s,
                                                   const float* __restrict__ w0,
                                                   const float* __restrict__ b0,
                                                   float* __restrict__ zx) {
    __shared__ float xf[PPH * PPW];
    const int t = blockIdx.x;
    const int tid = threadIdx.x;
    for (int i = tid; i < PPH * PPW; i += 256) xf[i] = 0.f;
    __syncthreads();
    const float* __restrict__ xs = s + (size_t)t * INLEN;
    for (int j = tid; j < INLEN; j += 256) {
        const int r = j / NCOL, c = j % NCOL;
        xf[(r + 1) * PPW + (c + 1)] = xs[j];
    }
    const float SC[4] = {-L2E, -L2E, -L2E, SGK};
    float wg[4][9], bb[4];
#pragma unroll
    for (int g = 0; g < 4; ++g) {
        bb[g] = b0[g] * SC[g];
#pragma unroll
        for (int k = 0; k < 9; ++k) wg[g][k] = w0[(g * 2 + 0) * 9 + k] * SC[g];
    }
    __syncthreads();
    f4* __restrict__ zt = (f4*)zx + (size_t)t * NCELL;
    for (int cell = tid; cell < NCELL; cell += 256) {
        const int r = cell / NCOL, c = cell % NCOL;
        const int p = (r + 1) * PPW + (c + 1);
        float z0 = bb[0], z1 = bb[1], z2 = bb[2], z3 = bb[3];
#pragma unroll
        for (int ky = 0; ky < 3; ++ky)
#pragma unroll
            for (int kx = 0; kx < 3; ++kx) {
                const float v = xf[p + (ky - 1) * PPW + (kx - 1)];
                const int k = ky * 3 + kx;
                z0 += wg[0][k] * v; z1 += wg[1][k] * v;
                z2 += wg[2][k] * v; z3 += wg[3][k] * v;
            }
        zt[cell] = (f4){z0, z1, z2, z3};
    }
}

// ============================================================================
// Scan: 1 workgroup, lane=col, wave w owns rows 5w..5w+4.
// One barrier/step; phase-B weights in SGPR pairs; fused-rcp exp2 gates.
// ============================================================================
__global__ __launch_bounds__(NTHR, 2) void convlstm_scan5(
        const float* __restrict__ zx,
        const float* __restrict__ w0g,
        const float* __restrict__ w1g, const float* __restrict__ b1g,
        float* __restrict__ feat) {
    // [parity][padded wave-row 0..9][0=row 5w, 1=row 5w+4][col]
    __shared__ float P0[2][10][2][64];
    __shared__ float P1[2][10][2][64];

    const int tid = threadIdx.x;
    const int w = tid >> 6;
    const int c = tid & 63;
    const float maskf = (c < NCOL) ? 1.f : 0.f;
    const int cmin = (c < NCOL) ? c : (NCOL - 1);

    {   // zero all LDS (pad rows 0/9 stay zero forever)
        float* p0 = &P0[0][0][0][0];
        float* p1 = &P1[0][0][0][0];
        for (int i = tid; i < 2 * 10 * 2 * 64; i += NTHR) { p0[i] = 0.f; p1[i] = 0.f; }
    }

    const float SA = -L2E;
    // phase-A weights (layer-0 h-conv): VGPR pairs, pinned
    f2 Wh0a[9], Wh0b[9];
#pragma unroll
    for (int k = 0; k < 9; ++k) {
        Wh0a[k] = (f2){w0g[ 9 + k] * SA, w0g[27 + k] * SA};
        Wh0b[k] = (f2){w0g[45 + k] * SA, w0g[63 + k] * SGK};
    }
#pragma unroll
    for (int k = 0; k < 9; ++k)
        asm volatile("" : "+v"(Wh0a[k]), "+v"(Wh0b[k]));

    // phase-B weights (layer-1 x- and h-conv): SGPR pairs
    i64 Sx1a[9], Sx1b[9], Sh1a[9], Sh1b[9];
#pragma unroll
    for (int k = 0; k < 9; ++k) {
        Sx1a[k] = mk_sw(w1g[ 0 + k] * SA, w1g[18 + k] * SA);
        Sx1b[k] = mk_sw(w1g[36 + k] * SA, w1g[54 + k] * SGK);
        Sh1a[k] = mk_sw(w1g[ 9 + k] * SA, w1g[27 + k] * SA);
        Sh1b[k] = mk_sw(w1g[45 + k] * SA, w1g[63 + k] * SGK);
    }
    f2 B1a = (f2){b1g[0] * SA, b1g[1] * SA};
    f2 B1b = (f2){b1g[2] * SA, b1g[3] * SGK};
    asm volatile("" : "+v"(B1a), "+v"(B1b));

    float sgkv = SGK;
    asm volatile("" : "+v"(sgkv));

    float h0[5] = {0,0,0,0,0}, c0[5] = {0,0,0,0,0};   // c-states pre-scaled by SGK
    float h1[5] = {0,0,0,0,0}, c1[5] = {0,0,0,0,0};

    // zx addressing: per-lane base + 32-bit step offset; 5 dwordx4 w/ imm offsets
    const char* __restrict__ zb = (const char*)zx;
    int voff = ((w * 5) * NCOL + cmin) * 16;

    f2 zA[5], zB[5];   // {i,f} and {o,g}; conv accumulates in place
    {
        const char* p = zb + voff;
#pragma unroll
        for (int i = 0; i < 5; ++i) {
            const f4 z4 = *(const f4*)(p + i * 800);
            zA[i] = __builtin_shufflevector(z4, z4, 0, 1);
            zB[i] = __builtin_shufflevector(z4, z4, 2, 3);
        }
    }
    voff += 32000;

    __syncthreads();

    for (int t = 0; t < TSTEPS; ++t) {
        const int pn = t & 1, pr_ = pn ^ 1;

        // ================= phase A : layer 0 =================
        {
            float e0[7];
            e0[0] = P0[pr_][w][1][c];          // row 5w-1 (pad row -> 0 at w=0)
            e0[6] = P0[pr_][w + 2][0][c];      // row 5w+5
#pragma unroll
            for (int i = 0; i < 5; ++i) e0[i + 1] = h0[i];
            conv5_v(e0, Wh0a, Wh0b, zA, zB);
        }
#pragma unroll
        for (int i = 0; i < 5; ++i)
            h0[i] = gates_update(zA[i], zB[i], c0[i], maskf, sgkv);
        P0[pn][w + 1][0][c] = h0[0];
        P0[pn][w + 1][1][c] = h0[4];

        // prefetch z(t+1) into the (now consumed) zA/zB
        {
            const char* p = zb + voff;
#pragma unroll
            for (int i = 0; i < 5; ++i) {
                const f4 z4 = *(const f4*)(p + i * 800);
                zA[i] = __builtin_shufflevector(z4, z4, 0, 1);
                zB[i] = __builtin_shufflevector(z4, z4, 2, 3);
            }
            if (t + 2 < TSTEPS) voff += 32000;
        }

        __syncthreads();   // the ONLY barrier per step

        // ================= phase B : layer 1 =================
        f2 uA[5], uB[5];
        {
            float ex[7];
            ex[0] = P0[pn][w][1][c];           // new h0 halos
            ex[6] = P0[pn][w + 2][0][c];
#pragma unroll
            for (int i = 0; i < 5; ++i) ex[i + 1] = h0[i];
            conv5_s<true>(ex, Sx1a, Sx1b, uA, uB, B1a, B1b);   // init with bias
        }
        {
            float eh[7];
            eh[0] = P1[pr_][w][1][c];          // old h1 halos
            eh[6] = P1[pr_][w + 2][0][c];
#pragma unroll
            for (int i = 0; i < 5; ++i) eh[i + 1] = h1[i];
            conv5_s<false>(eh, Sh1a, Sh1b, uA, uB, B1a, B1b);
        }
#pragma unroll
        for (int i = 0; i < 5; ++i)
            h1[i] = gates_update(uA[i], uB[i], c1[i], maskf, sgkv);
        P1[pn][w + 1][0][c] = h1[0];
        P1[pn][w + 1][1][c] = h1[4];
        // no trailing barrier: next step's phase A touches only P0[pr_], and the
        // next __syncthreads orders these P1 writes before their phase-B readers.
    }

    if (c < NCOL) {
#pragma unroll
        for (int i = 0; i < 5; ++i)
            feat[(w * 5 + i) * NCOL + c] = h1[i];
    }
}

// ============================================================================
// Fallback monolithic scan (round-1, known-correct; used only if ws too small)
// ============================================================================
#define PW 52
#define PH 42
__device__ __forceinline__ void cell_update(const float* __restrict__ xf,
                                            const float* __restrict__ hf,
                                            const float (&wr)[72], const float (&br)[4],
                                            const int (&pidx)[4],
                                            float (&cst)[4], float (&hn)[4]) {
#pragma unroll
    for (int q = 0; q < 4; ++q) {
        const int p = pidx[q];
        float z0 = br[0], z1 = br[1], z2 = br[2], z3 = br[3];
#pragma unroll
        for (int ky = 0; ky < 3; ++ky)
#pragma unroll
            for (int kx = 0; kx < 3; ++kx) {
                const int off = (ky - 1) * PW + (kx - 1);
                const float xval = xf[p + off];
                const float hval = hf[p + off];
                const int wi = ky * 3 + kx;
                z0 += wr[ 0 + wi] * xval + wr[ 9 + wi] * hval;
                z1 += wr[18 + wi] * xval + wr[27 + wi] * hval;
                z2 += wr[36 + wi] * xval + wr[45 + wi] * hval;
                z3 += wr[54 + wi] * xval + wr[63 + wi] * hval;
            }
        const float ig = sigm(z0), fg = sigm(z1), og = sigm(z2), gg = tanh_f(z3);
        const float cn = fg * cst[q] + ig * gg;
        cst[q] = cn;
        hn[q]  = og * tanh_f(cn);
    }
}

__global__ __launch_bounds__(NTHR, 2) void convlstm_scan(
    const float* __restrict__ s,
    const float* __restrict__ w0g, const float* __restrict__ b0g,
    const float* __restrict__ w1g, const float* __restrict__ b1g,
    float* __restrict__ feat) {
    __shared__ float xb[PH * PW];
    __shared__ float h0[PH * PW];
    __shared__ float h1[PH * PW];
    const int tid = threadIdx.x;
    for (int i = tid; i < PH * PW; i += NTHR) { xb[i] = 0.f; h0[i] = 0.f; h1[i] = 0.f; }
    float w0r[72], w1r[72], b0r[4], b1r[4];
#pragma unroll
    for (int i = 0; i < 72; ++i) w0r[i] = w0g[i];
#pragma unroll
    for (int i = 0; i < 72; ++i) w1r[i] = w1g[i];
#pragma unroll
    for (int i = 0; i < 4; ++i) { b0r[i] = b0g[i]; b1r[i] = b1g[i]; }
    int pidx[4]; bool cv[4];
#pragma unroll
    for (int q = 0; q < 4; ++q) {
        int cell = tid + q * NTHR;
        cv[q] = (cell < NCELL);
        if (!cv[q]) cell = 0;
        const int r = cell / NCOL, cc = cell % NCOL;
        pidx[q] = (r + 1) * PW + (cc + 1);
    }
    int xjj[4], xpp[4]; bool xv[4];
#pragma unroll
    for (int k = 0; k < 4; ++k) {
        int j = tid + k * NTHR;
        xv[k] = (j < INLEN);
        if (!xv[k]) j = 0;
        xjj[k] = j;
        const int r = j / NCOL, cc = j % NCOL;
        xpp[k] = (r + 1) * PW + (cc + 1);
    }
    float c0r[4] = {0,0,0,0}, c1r[4] = {0,0,0,0};
    float xr[4];
#pragma unroll
    for (int k = 0; k < 4; ++k) xr[k] = xv[k] ? s[xjj[k]] : 0.f;
    __syncthreads();
    for (int t = 0; t < TSTEPS; ++t) {
#pragma unroll
        for (int k = 0; k < 4; ++k)
            if (xv[k]) xb[xpp[k]] = xr[k];
        {
            const size_t bofs = (size_t)(t + 1 < TSTEPS ? t + 1 : t) * INLEN;
#pragma unroll
            for (int k = 0; k < 4; ++k) xr[k] = xv[k] ? s[bofs + xjj[k]] : 0.f;
        }
        __syncthreads();
        float hn0[4];
        cell_update(xb, h0, w0r, b0r, pidx, c0r, hn0);
        __syncthreads();
#pragma unroll
        for (int q = 0; q < 4; ++q)
            if (cv[q]) h0[pidx[q]] = hn0[q];
        __syncthreads();
        float hn1[4];
        cell_update(h0, h1, w1r, b1r, pidx, c1r, hn1);
        __syncthreads();
#pragma unroll
        for (int q = 0; q < 4; ++q)
            if (cv[q]) h1[pidx[q]] = hn1[q];
    }
#pragma unroll
    for (int q = 0; q < 4; ++q)
        if (cv[q]) feat[tid + q * NTHR] = h1[pidx[q]];
}

// ============================================================================
// FC epilogue
// ============================================================================
__global__ __launch_bounds__(256) void fc_kernel(const float* __restrict__ feat,
                                                 const float* __restrict__ w,
                                                 const float* __restrict__ b,
                                                 float* __restrict__ out) {
    const int j   = blockIdx.x;
    const int tid = threadIdx.x;
    const float* __restrict__ wr = w + (size_t)j * NCELL;
    float acc = 0.f;
    for (int k = tid; k < NCELL; k += 256) {
        float f = feat[k];
        f = (f > 0.f) ? f : 0.01f * f;
        acc += f * wr[k];
    }
#pragma unroll
    for (int off = 32; off > 0; off >>= 1) acc += __shfl_down(acc, off, 64);
    __shared__ float red[4];
    const int wv = tid >> 6, ln = tid & 63;
    if (ln == 0) red[wv] = acc;
    __syncthreads();
    if (tid == 0) {
        const float a = red[0] + red[1] + red[2] + red[3] + b[j];
        out[j] = fastrcp(1.0f + __expf(-a));
    }
}

extern "C" void kernel_launch(void* const* d_in, const int* in_sizes, int n_in,
                              void* d_out, int out_size, void* d_ws, size_t ws_size,
                              hipStream_t stream) {
    const float* s   = (const float*)d_in[0];
    const float* w0  = (const float*)d_in[1];
    const float* b0  = (const float*)d_in[2];
    const float* w1  = (const float*)d_in[3];
    const float* b1  = (const float*)d_in[4];
    const float* fcw = (const float*)d_in[5];
    const float* fcb = (const float*)d_in[6];
    float* out  = (float*)d_out;
    float* feat = (float*)d_ws;   // 2000 floats

    const size_t zx_bytes = (size_t)TSTEPS * NCELL * 4 * sizeof(float);
    if (ws_size >= zx_bytes + 8192) {
        float* zx = (float*)((char*)d_ws + 8192);
        zx_prepass4<<<TSTEPS, 256, 0, stream>>>(s, w0, b0, zx);
        convlstm_scan5<<<1, NTHR, 0, stream>>>(zx, w0, w1, b1, feat);
    } else {
        convlstm_scan<<<1, NTHR, 0, stream>>>(s, w0, b0, w1, b1, feat);
    }
    fc_kernel<<<NCELL, 256, 0, stream>>>(feat, fcw, fcb, out);
}